// Round 1
// baseline (1363.966 us; speedup 1.0000x reference)
//
#include <hip/hip_runtime.h>
#include <hip/hip_bf16.h>
#include <math.h>

#define NN 50000
#define EE 800000
#define HC 128
#define FF 32
#define NEG 0.2f

// ---------------- CSR build ----------------

__global__ void k_hist(const int* __restrict__ dst, int* __restrict__ deg) {
    int e = blockIdx.x * 256 + threadIdx.x;
    if (e < EE) atomicAdd(&deg[dst[e]], 1);
}

// chunk = 1024 elements per block (256 thr x 4)
__global__ void k_scan1(const int* __restrict__ deg, int* __restrict__ part) {
    __shared__ int sd[256];
    int b = blockIdx.x, t = threadIdx.x;
    int base = b * 1024 + t * 4;
    int s = 0;
#pragma unroll
    for (int i = 0; i < 4; ++i) { int idx = base + i; if (idx < NN) s += deg[idx]; }
    sd[t] = s; __syncthreads();
    for (int off = 128; off; off >>= 1) { if (t < off) sd[t] += sd[t + off]; __syncthreads(); }
    if (t == 0) part[b] = sd[0];
}

__global__ void k_scan2(int* __restrict__ part, int nb) {
    if (threadIdx.x == 0) {
        int run = 0;
        for (int i = 0; i < nb; ++i) { int v = part[i]; part[i] = run; run += v; }
    }
}

__global__ void k_scan3(const int* __restrict__ deg, const int* __restrict__ part,
                        int* __restrict__ rowptr) {
    __shared__ int sd[256];
    int b = blockIdx.x, t = threadIdx.x;
    int base = b * 1024 + t * 4;
    int v[4]; int mine = 0;
#pragma unroll
    for (int i = 0; i < 4; ++i) { int idx = base + i; v[i] = (idx < NN) ? deg[idx] : 0; mine += v[i]; }
    sd[t] = mine; __syncthreads();
    for (int off = 1; off < 256; off <<= 1) {
        int tmp = (t >= off) ? sd[t - off] : 0;
        __syncthreads();
        sd[t] += tmp;
        __syncthreads();
    }
    int run = sd[t] - mine + part[b];
#pragma unroll
    for (int i = 0; i < 4; ++i) { int idx = base + i; if (idx < NN) rowptr[idx] = run; run += v[i]; }
    if (b == 0 && t == 0) rowptr[NN] = EE;
}

__global__ void k_scatter(const int* __restrict__ src, const int* __restrict__ dst,
                          const float* __restrict__ ea, const int* __restrict__ rowptr,
                          int* __restrict__ fill, int* __restrict__ ssrc,
                          float* __restrict__ sea) {
    int e = blockIdx.x * 256 + threadIdx.x;
    if (e >= EE) return;
    int d = dst[e];
    int pos = rowptr[d] + atomicAdd(&fill[d], 1);
    ssrc[pos] = src[e];
    sea[pos] = fabsf(ea[e]);
}

// ---------------- dual linear: xl = x@Wl+bl, xr = x@Wr+br ----------------
// block 256: thread t -> half = t>>7 (0:xl 1:xr), col = t&127; 8 nodes per tile

__global__ __launch_bounds__(256) void k_dual_linear(
        const float* __restrict__ x,
        const float* __restrict__ Wl, const float* __restrict__ bl,
        const float* __restrict__ Wr, const float* __restrict__ br,
        float* __restrict__ xl, float* __restrict__ xr, int nTiles) {
    __shared__ float sW[2][FF * HC];   // 32 KB
    __shared__ float sX[8][FF];        // 1 KB
    int t = threadIdx.x;
    for (int i = t; i < FF * HC; i += 256) { sW[0][i] = Wl[i]; sW[1][i] = Wr[i]; }
    int half = t >> 7;
    int ct = t & 127;
    float b = half ? br[ct] : bl[ct];
    float* outp = half ? xr : xl;
    for (int tile = blockIdx.x; tile < nTiles; tile += gridDim.x) {
        int base = tile * 8;
        __syncthreads();
        sX[t >> 5][t & 31] = x[(base + (t >> 5)) * FF + (t & 31)];
        __syncthreads();
        float acc[8];
#pragma unroll
        for (int ni = 0; ni < 8; ++ni) acc[ni] = b;
#pragma unroll
        for (int k = 0; k < FF; ++k) {
            float w = sW[half][k * HC + ct];
#pragma unroll
            for (int ni = 0; ni < 8; ++ni) acc[ni] += sX[ni][k] * w;
        }
#pragma unroll
        for (int ni = 0; ni < 8; ++ni) outp[(base + ni) * HC + ct] = acc[ni];
    }
}

// ---------------- fused GATv2 edge-softmax + aggregate ----------------
// 128 threads per dst node (channel each), 2 nodes per 256-block.
// Pass A: online softmax over in-edges (per-head logits via 32-lane butterfly).
// Pass C: re-gather xl rows, recompute logit, accumulate alpha * xj.

__global__ __launch_bounds__(256) void k_gat_agg(
        const float* __restrict__ xl, const float* __restrict__ xr,
        const int* __restrict__ rowptr, const int* __restrict__ ssrc,
        const float* __restrict__ sea,
        const float* __restrict__ att,   // [4*32]
        const float* __restrict__ Wev,   // [128]
        const float* __restrict__ cb,    // [128]
        float* __restrict__ outb) {
    int t = threadIdx.x & 127;
    int n = blockIdx.x * 2 + (threadIdx.x >> 7);
    if (n >= NN) return;
    float att_v = att[t];          // att flat [h*32+c] == t
    float we_v = Wev[t];
    float xr_v = xr[n * HC + t];
    int beg = rowptr[n], end = rowptr[n + 1];

    float m = -INFINITY, s = 0.f;
    for (int j = beg; j < end; ++j) {
        float xj = xl[ssrc[j] * HC + t];
        float v = xr_v + xj + sea[j] * we_v;
        v = v > 0.f ? v : NEG * v;
        float l = v * att_v;
#pragma unroll
        for (int off = 16; off; off >>= 1) l += __shfl_xor(l, off, 64);
        float mn = fmaxf(m, l);
        s = s * __expf(m - mn) + __expf(l - mn);
        m = mn;
    }
    float inv = (s > 0.f) ? 1.f / s : 0.f;
    float acc = 0.f;
    for (int j = beg; j < end; ++j) {
        float xj = xl[ssrc[j] * HC + t];
        float v = xr_v + xj + sea[j] * we_v;
        v = v > 0.f ? v : NEG * v;
        float l = v * att_v;
#pragma unroll
        for (int off = 16; off; off >>= 1) l += __shfl_xor(l, off, 64);
        acc += __expf(l - m) * inv * xj;
    }
    outb[n * HC + t] = acc + cb[t];
}

// ---------------- per-node MLP + BN: h = leaky(out@lW+lb)*bsc+bsh ----------------
// block 256: 8 nodes x 32 cols

__global__ __launch_bounds__(256) void k_mlp_bn(
        const float* __restrict__ outb,
        const float* __restrict__ lW, const float* __restrict__ lb,
        const float* __restrict__ bsc, const float* __restrict__ bsh,
        float* __restrict__ h, int nTiles) {
    __shared__ float sW[HC * FF];  // 16 KB
    __shared__ float sO[8 * HC];   // 4 KB
    int t = threadIdx.x;
    for (int i = t; i < HC * FF; i += 256) sW[i] = lW[i];
    int ln = t >> 5, f = t & 31;
    float b = lb[f], sc = bsc[f], sh = bsh[f];
    for (int tile = blockIdx.x; tile < nTiles; tile += gridDim.x) {
        int base = tile * 8;
        __syncthreads();
#pragma unroll
        for (int i = 0; i < 4; ++i) sO[t + i * 256] = outb[base * HC + t + i * 256];
        __syncthreads();
        float acc = b;
#pragma unroll
        for (int c = 0; c < HC; ++c) acc += sO[ln * HC + c] * sW[c * FF + f];
        acc = acc > 0.f ? acc : NEG * acc;
        h[(base + ln) * FF + f] = acc * sc + sh;
    }
}

// ---------------- global mean pool (column sums) ----------------

__global__ void k_colsum(const float* __restrict__ h, float* __restrict__ g) {
    __shared__ float sd[256];
    int t = threadIdx.x;
    int col = t & 31, r = t >> 5;
    float local = 0.f;
    for (int row = blockIdx.x * 8 + r; row < NN; row += gridDim.x * 8)
        local += h[row * FF + col];
    sd[t] = local; __syncthreads();
    if (r < 4) sd[t] += sd[t + 128];
    __syncthreads();
    if (r < 2) sd[t] += sd[t + 64];
    __syncthreads();
    if (r < 1) atomicAdd(&g[col], sd[t] + sd[t + 32]);
}

// ---------------- head MLP: 32 -> 256 -> 32 -> 2 ----------------

__global__ void k_head(const float* __restrict__ g,
                       const float* __restrict__ W1, const float* __restrict__ b1,
                       const float* __restrict__ W2, const float* __restrict__ b2,
                       const float* __restrict__ W3, const float* __restrict__ b3,
                       float* __restrict__ out) {
    __shared__ float gv[32];
    __shared__ float h1[256];
    __shared__ float h2[32];
    int t = threadIdx.x;
    if (t < 32) gv[t] = g[t] * (1.0f / NN);
    __syncthreads();
    float acc = b1[t];
#pragma unroll 8
    for (int k = 0; k < 32; ++k) acc += gv[k] * W1[k * 256 + t];
    h1[t] = acc > 0.f ? acc : NEG * acc;
    __syncthreads();
    if (t < 32) {
        float a = b2[t];
        for (int k = 0; k < 256; ++k) a += h1[k] * W2[k * 32 + t];
        h2[t] = a > 0.f ? a : NEG * a;
    }
    __syncthreads();
    if (t < 2) {
        float a = b3[t];
#pragma unroll
        for (int k = 0; k < 32; ++k) a += h2[k] * W3[k * 2 + t];
        out[t] = a;
    }
}

// ---------------- host ----------------

static inline size_t alignup(size_t x) { return (x + 255) & ~size_t(255); }

extern "C" void kernel_launch(void* const* d_in, const int* in_sizes, int n_in,
                              void* d_out, int out_size, void* d_ws, size_t ws_size,
                              hipStream_t stream) {
    const float* x     = (const float*)d_in[0];
    const int*   eidx  = (const int*)d_in[1];
    const float* eattr = (const float*)d_in[2];
    // d_in[3] = batch (all zeros, unused)
    const float* Wl    = (const float*)d_in[4];
    const float* bl    = (const float*)d_in[5];
    const float* Wr    = (const float*)d_in[6];
    const float* br    = (const float*)d_in[7];
    const float* att   = (const float*)d_in[8];
    const float* We    = (const float*)d_in[9];
    const float* cb    = (const float*)d_in[10];
    const float* lW    = (const float*)d_in[11];
    const float* lb    = (const float*)d_in[12];
    const float* bsc   = (const float*)d_in[13];
    const float* bsh   = (const float*)d_in[14];
    const float* W1    = (const float*)d_in[15];
    const float* b1    = (const float*)d_in[16];
    const float* W2    = (const float*)d_in[17];
    const float* b2    = (const float*)d_in[18];
    const float* W3    = (const float*)d_in[19];
    const float* b3    = (const float*)d_in[20];

    const int* srcp = eidx;
    const int* dstp = eidx + EE;

    char* ws = (char*)d_ws;
    size_t off = 0;
    float* xl     = (float*)(ws + off); off += alignup((size_t)NN * HC * 4);
    float* xr     = (float*)(ws + off); off += alignup((size_t)NN * HC * 4);
    float* outb   = (float*)(ws + off); off += alignup((size_t)NN * HC * 4);
    float* hA     = (float*)(ws + off); off += alignup((size_t)NN * FF * 4);
    float* hB     = (float*)(ws + off); off += alignup((size_t)NN * FF * 4);
    int*   ssrc   = (int*)  (ws + off); off += alignup((size_t)EE * 4);
    float* sea    = (float*)(ws + off); off += alignup((size_t)EE * 4);
    int*   rowptr = (int*)  (ws + off); off += alignup((size_t)(NN + 1) * 4);
    int*   deg    = (int*)  (ws + off); off += alignup((size_t)NN * 4);
    int*   fill   = (int*)  (ws + off); off += alignup((size_t)NN * 4);
    int*   part   = (int*)  (ws + off); off += alignup(64 * 4);
    float* g      = (float*)(ws + off); off += alignup(32 * 4);

    hipMemsetAsync(deg, 0, (size_t)NN * 4, stream);
    hipMemsetAsync(fill, 0, (size_t)NN * 4, stream);
    hipMemsetAsync(g, 0, 32 * 4, stream);

    const int nChunk = (NN + 1023) / 1024;  // 49
    k_hist<<<(EE + 255) / 256, 256, 0, stream>>>(dstp, deg);
    k_scan1<<<nChunk, 256, 0, stream>>>(deg, part);
    k_scan2<<<1, 64, 0, stream>>>(part, nChunk);
    k_scan3<<<nChunk, 256, 0, stream>>>(deg, part, rowptr);
    k_scatter<<<(EE + 255) / 256, 256, 0, stream>>>(srcp, dstp, eattr, rowptr, fill, ssrc, sea);

    const int nTiles = NN / 8;  // 6250
    const float* cur = x;
    float* hbuf[2] = {hA, hB};
    for (int i = 0; i < 3; ++i) {
        k_dual_linear<<<512, 256, 0, stream>>>(cur, Wl + i * FF * HC, bl + i * HC,
                                               Wr + i * FF * HC, br + i * HC, xl, xr, nTiles);
        k_gat_agg<<<NN / 2, 256, 0, stream>>>(xl, xr, rowptr, ssrc, sea,
                                              att + i * HC, We + i * HC, cb + i * HC, outb);
        k_mlp_bn<<<512, 256, 0, stream>>>(outb, lW + i * HC * FF, lb + i * FF,
                                          bsc + i * FF, bsh + i * FF, hbuf[i & 1], nTiles);
        cur = hbuf[i & 1];
    }

    k_colsum<<<128, 256, 0, stream>>>(cur, g);
    k_head<<<1, 256, 0, stream>>>(g, W1, b1, W2, b2, W3, b3, (float*)d_out);
}

// Round 2
// 779.789 us; speedup vs baseline: 1.7491x; 1.7491x over previous
//
#include <hip/hip_runtime.h>
#include <hip/hip_bf16.h>
#include <math.h>

#define NN 50000
#define EE 800000
#define HC 128
#define FF 32
#define NEG 0.2f

// ---------------- CSR build ----------------

__global__ void k_hist(const int* __restrict__ dst, int* __restrict__ deg) {
    int e = blockIdx.x * 256 + threadIdx.x;
    if (e < EE) atomicAdd(&deg[dst[e]], 1);
}

// chunk = 1024 elements per block (256 thr x 4)
__global__ void k_scan1(const int* __restrict__ deg, int* __restrict__ part) {
    __shared__ int sd[256];
    int b = blockIdx.x, t = threadIdx.x;
    int base = b * 1024 + t * 4;
    int s = 0;
#pragma unroll
    for (int i = 0; i < 4; ++i) { int idx = base + i; if (idx < NN) s += deg[idx]; }
    sd[t] = s; __syncthreads();
    for (int off = 128; off; off >>= 1) { if (t < off) sd[t] += sd[t + off]; __syncthreads(); }
    if (t == 0) part[b] = sd[0];
}

__global__ void k_scan2(int* __restrict__ part, int nb) {
    if (threadIdx.x == 0) {
        int run = 0;
        for (int i = 0; i < nb; ++i) { int v = part[i]; part[i] = run; run += v; }
    }
}

__global__ void k_scan3(const int* __restrict__ deg, const int* __restrict__ part,
                        int* __restrict__ rowptr) {
    __shared__ int sd[256];
    int b = blockIdx.x, t = threadIdx.x;
    int base = b * 1024 + t * 4;
    int v[4]; int mine = 0;
#pragma unroll
    for (int i = 0; i < 4; ++i) { int idx = base + i; v[i] = (idx < NN) ? deg[idx] : 0; mine += v[i]; }
    sd[t] = mine; __syncthreads();
    for (int off = 1; off < 256; off <<= 1) {
        int tmp = (t >= off) ? sd[t - off] : 0;
        __syncthreads();
        sd[t] += tmp;
        __syncthreads();
    }
    int run = sd[t] - mine + part[b];
#pragma unroll
    for (int i = 0; i < 4; ++i) { int idx = base + i; if (idx < NN) rowptr[idx] = run; run += v[i]; }
    if (b == 0 && t == 0) rowptr[NN] = EE;
}

// pack (src, |ea|) into int2 so the agg kernel does one 8B load per edge
__global__ void k_scatter(const int* __restrict__ src, const int* __restrict__ dst,
                          const float* __restrict__ ea, const int* __restrict__ rowptr,
                          int* __restrict__ fill, int2* __restrict__ pairs) {
    int e = blockIdx.x * 256 + threadIdx.x;
    if (e >= EE) return;
    int d = dst[e];
    int pos = rowptr[d] + atomicAdd(&fill[d], 1);
    pairs[pos] = make_int2(src[e], __float_as_int(fabsf(ea[e])));
}

// ---------------- dual linear: xl = x@Wl+bl, xr = x@Wr+br ----------------

__global__ __launch_bounds__(256) void k_dual_linear(
        const float* __restrict__ x,
        const float* __restrict__ Wl, const float* __restrict__ bl,
        const float* __restrict__ Wr, const float* __restrict__ br,
        float* __restrict__ xl, float* __restrict__ xr, int nTiles) {
    __shared__ float sW[2][FF * HC];   // 32 KB
    __shared__ float sX[8][FF];        // 1 KB
    int t = threadIdx.x;
    for (int i = t; i < FF * HC; i += 256) { sW[0][i] = Wl[i]; sW[1][i] = Wr[i]; }
    int half = t >> 7;
    int ct = t & 127;
    float b = half ? br[ct] : bl[ct];
    float* outp = half ? xr : xl;
    for (int tile = blockIdx.x; tile < nTiles; tile += gridDim.x) {
        int base = tile * 8;
        __syncthreads();
        sX[t >> 5][t & 31] = x[(base + (t >> 5)) * FF + (t & 31)];
        __syncthreads();
        float acc[8];
#pragma unroll
        for (int ni = 0; ni < 8; ++ni) acc[ni] = b;
#pragma unroll
        for (int k = 0; k < FF; ++k) {
            float w = sW[half][k * HC + ct];
#pragma unroll
            for (int ni = 0; ni < 8; ++ni) acc[ni] += sX[ni][k] * w;
        }
#pragma unroll
        for (int ni = 0; ni < 8; ++ni) outp[(base + ni) * HC + ct] = acc[ni];
    }
}

// ---------------- fused GATv2 edge-softmax + aggregate ----------------
// 32 threads per dst node (float4 = 4 channels each), 8 nodes per 256-block.
// Pass A: gather xl rows, per-head logit via 4-ch dot + 3-step shfl butterfly,
//         running fmax only (no exp in chain); optionally store logit [E][4].
// Pass C: re-gather xl rows, e = exp(l - m); s += e; acc += e*xj; out = acc/s.

template<int USE_LG>
__global__ __launch_bounds__(256) void k_gat_agg(
        const float* __restrict__ xl, const float* __restrict__ xr,
        const int* __restrict__ rowptr, const int2* __restrict__ pairs,
        const float* __restrict__ att,   // [128]
        const float* __restrict__ Wev,   // [128]
        const float* __restrict__ cb,    // [128]
        float* __restrict__ lg,          // [E*4] scratch (USE_LG)
        float* __restrict__ outb) {
    const int l = threadIdx.x & 31;          // lane within node group
    const int n = blockIdx.x * 8 + (threadIdx.x >> 5);
    const int h = l >> 3;                    // head
    const float4* __restrict__ xl4 = (const float4*)xl;

    float4 att4 = ((const float4*)att)[l];
    float4 we4  = ((const float4*)Wev)[l];
    float4 xr4  = ((const float4*)xr)[n * 32 + l];
    const int beg = rowptr[n], end = rowptr[n + 1];

    // ---- pass A: logits + running max ----
    float m = -INFINITY;
    int2 p = make_int2(0, 0);
    float4 xj = make_float4(0.f, 0.f, 0.f, 0.f);
    if (beg < end) { p = pairs[beg]; xj = xl4[(size_t)p.x * 32 + l]; }
    for (int j = beg; j < end; ++j) {
        int2 pn = p; float4 xjn = xj;
        if (j + 1 < end) { pn = pairs[j + 1]; xjn = xl4[(size_t)pn.x * 32 + l]; }
        float sea = __int_as_float(p.y);
        float4 v;
        v.x = xr4.x + xj.x + sea * we4.x;
        v.y = xr4.y + xj.y + sea * we4.y;
        v.z = xr4.z + xj.z + sea * we4.z;
        v.w = xr4.w + xj.w + sea * we4.w;
        v.x = v.x > 0.f ? v.x : NEG * v.x;
        v.y = v.y > 0.f ? v.y : NEG * v.y;
        v.z = v.z > 0.f ? v.z : NEG * v.z;
        v.w = v.w > 0.f ? v.w : NEG * v.w;
        float pl = v.x * att4.x + v.y * att4.y + v.z * att4.z + v.w * att4.w;
        pl += __shfl_xor(pl, 4);
        pl += __shfl_xor(pl, 2);
        pl += __shfl_xor(pl, 1);
        m = fmaxf(m, pl);
        if (USE_LG && (l & 7) == 0) lg[(size_t)j * 4 + h] = pl;
        p = pn; xj = xjn;
    }

    // ---- pass C: weights + aggregate + denominator ----
    float s = 0.f;
    float4 acc = make_float4(0.f, 0.f, 0.f, 0.f);
    p = make_int2(0, 0);
    if (beg < end) { p = pairs[beg]; xj = xl4[(size_t)p.x * 32 + l]; }
    for (int j = beg; j < end; ++j) {
        int2 pn = p; float4 xjn = xj;
        if (j + 1 < end) { pn = pairs[j + 1]; xjn = xl4[(size_t)pn.x * 32 + l]; }
        float pl;
        if (USE_LG) {
            pl = lg[(size_t)j * 4 + h];
        } else {
            float sea = __int_as_float(p.y);
            float4 v;
            v.x = xr4.x + xj.x + sea * we4.x;
            v.y = xr4.y + xj.y + sea * we4.y;
            v.z = xr4.z + xj.z + sea * we4.z;
            v.w = xr4.w + xj.w + sea * we4.w;
            v.x = v.x > 0.f ? v.x : NEG * v.x;
            v.y = v.y > 0.f ? v.y : NEG * v.y;
            v.z = v.z > 0.f ? v.z : NEG * v.z;
            v.w = v.w > 0.f ? v.w : NEG * v.w;
            pl = v.x * att4.x + v.y * att4.y + v.z * att4.z + v.w * att4.w;
            pl += __shfl_xor(pl, 4);
            pl += __shfl_xor(pl, 2);
            pl += __shfl_xor(pl, 1);
        }
        float e = __expf(pl - m);
        s += e;
        acc.x += e * xj.x;
        acc.y += e * xj.y;
        acc.z += e * xj.z;
        acc.w += e * xj.w;
        p = pn; xj = xjn;
    }
    float inv = (s > 0.f) ? 1.f / s : 0.f;
    float4 cb4 = ((const float4*)cb)[l];
    float4 o;
    o.x = acc.x * inv + cb4.x;
    o.y = acc.y * inv + cb4.y;
    o.z = acc.z * inv + cb4.z;
    o.w = acc.w * inv + cb4.w;
    ((float4*)outb)[n * 32 + l] = o;
}

// ---------------- per-node MLP + BN ----------------

__global__ __launch_bounds__(256) void k_mlp_bn(
        const float* __restrict__ outb,
        const float* __restrict__ lW, const float* __restrict__ lb,
        const float* __restrict__ bsc, const float* __restrict__ bsh,
        float* __restrict__ h, int nTiles) {
    __shared__ float sW[HC * FF];  // 16 KB
    __shared__ float sO[8 * HC];   // 4 KB
    int t = threadIdx.x;
    for (int i = t; i < HC * FF; i += 256) sW[i] = lW[i];
    int ln = t >> 5, f = t & 31;
    float b = lb[f], sc = bsc[f], sh = bsh[f];
    for (int tile = blockIdx.x; tile < nTiles; tile += gridDim.x) {
        int base = tile * 8;
        __syncthreads();
#pragma unroll
        for (int i = 0; i < 4; ++i) sO[t + i * 256] = outb[base * HC + t + i * 256];
        __syncthreads();
        float acc = b;
#pragma unroll
        for (int c = 0; c < HC; ++c) acc += sO[ln * HC + c] * sW[c * FF + f];
        acc = acc > 0.f ? acc : NEG * acc;
        h[(base + ln) * FF + f] = acc * sc + sh;
    }
}

// ---------------- global mean pool (column sums) ----------------

__global__ void k_colsum(const float* __restrict__ h, float* __restrict__ g) {
    __shared__ float sd[256];
    int t = threadIdx.x;
    int col = t & 31, r = t >> 5;
    float local = 0.f;
    for (int row = blockIdx.x * 8 + r; row < NN; row += gridDim.x * 8)
        local += h[row * FF + col];
    sd[t] = local; __syncthreads();
    if (r < 4) sd[t] += sd[t + 128];
    __syncthreads();
    if (r < 2) sd[t] += sd[t + 64];
    __syncthreads();
    if (r < 1) atomicAdd(&g[col], sd[t] + sd[t + 32]);
}

// ---------------- head MLP: 32 -> 256 -> 32 -> 2 ----------------

__global__ void k_head(const float* __restrict__ g,
                       const float* __restrict__ W1, const float* __restrict__ b1,
                       const float* __restrict__ W2, const float* __restrict__ b2,
                       const float* __restrict__ W3, const float* __restrict__ b3,
                       float* __restrict__ out) {
    __shared__ float gv[32];
    __shared__ float h1[256];
    __shared__ float h2[32];
    int t = threadIdx.x;
    if (t < 32) gv[t] = g[t] * (1.0f / NN);
    __syncthreads();
    float acc = b1[t];
#pragma unroll 8
    for (int k = 0; k < 32; ++k) acc += gv[k] * W1[k * 256 + t];
    h1[t] = acc > 0.f ? acc : NEG * acc;
    __syncthreads();
    if (t < 32) {
        float a = b2[t];
        for (int k = 0; k < 256; ++k) a += h1[k] * W2[k * 32 + t];
        h2[t] = a > 0.f ? a : NEG * a;
    }
    __syncthreads();
    if (t < 2) {
        float a = b3[t];
#pragma unroll
        for (int k = 0; k < 32; ++k) a += h2[k] * W3[k * 2 + t];
        out[t] = a;
    }
}

// ---------------- host ----------------

static inline size_t alignup(size_t x) { return (x + 255) & ~size_t(255); }

extern "C" void kernel_launch(void* const* d_in, const int* in_sizes, int n_in,
                              void* d_out, int out_size, void* d_ws, size_t ws_size,
                              hipStream_t stream) {
    const float* x     = (const float*)d_in[0];
    const int*   eidx  = (const int*)d_in[1];
    const float* eattr = (const float*)d_in[2];
    const float* Wl    = (const float*)d_in[4];
    const float* bl    = (const float*)d_in[5];
    const float* Wr    = (const float*)d_in[6];
    const float* br    = (const float*)d_in[7];
    const float* att   = (const float*)d_in[8];
    const float* We    = (const float*)d_in[9];
    const float* cb    = (const float*)d_in[10];
    const float* lW    = (const float*)d_in[11];
    const float* lb    = (const float*)d_in[12];
    const float* bsc   = (const float*)d_in[13];
    const float* bsh   = (const float*)d_in[14];
    const float* W1    = (const float*)d_in[15];
    const float* b1    = (const float*)d_in[16];
    const float* W2    = (const float*)d_in[17];
    const float* b2    = (const float*)d_in[18];
    const float* W3    = (const float*)d_in[19];
    const float* b3    = (const float*)d_in[20];

    const int* srcp = eidx;
    const int* dstp = eidx + EE;

    char* ws = (char*)d_ws;
    size_t off = 0;
    float* xl     = (float*)(ws + off); off += alignup((size_t)NN * HC * 4);
    float* xr     = (float*)(ws + off); off += alignup((size_t)NN * HC * 4);
    float* outb   = (float*)(ws + off); off += alignup((size_t)NN * HC * 4);
    float* hA     = (float*)(ws + off); off += alignup((size_t)NN * FF * 4);
    float* hB     = (float*)(ws + off); off += alignup((size_t)NN * FF * 4);
    int2*  pairs  = (int2*) (ws + off); off += alignup((size_t)EE * 8);
    int*   rowptr = (int*)  (ws + off); off += alignup((size_t)(NN + 1) * 4);
    int*   deg    = (int*)  (ws + off); off += alignup((size_t)NN * 4);
    int*   fill   = (int*)  (ws + off); off += alignup((size_t)NN * 4);
    int*   part   = (int*)  (ws + off); off += alignup(64 * 4);
    float* g      = (float*)(ws + off); off += alignup(32 * 4);
    float* lg     = (float*)(ws + off);
    size_t off_lg = off + alignup((size_t)EE * 4 * 4);
    const bool use_lg = (ws_size >= off_lg);

    hipMemsetAsync(deg, 0, (size_t)NN * 4, stream);
    hipMemsetAsync(fill, 0, (size_t)NN * 4, stream);
    hipMemsetAsync(g, 0, 32 * 4, stream);

    const int nChunk = (NN + 1023) / 1024;  // 49
    k_hist<<<(EE + 255) / 256, 256, 0, stream>>>(dstp, deg);
    k_scan1<<<nChunk, 256, 0, stream>>>(deg, part);
    k_scan2<<<1, 64, 0, stream>>>(part, nChunk);
    k_scan3<<<nChunk, 256, 0, stream>>>(deg, part, rowptr);
    k_scatter<<<(EE + 255) / 256, 256, 0, stream>>>(srcp, dstp, eattr, rowptr, fill, pairs);

    const int nTiles = NN / 8;  // 6250
    const float* cur = x;
    float* hbuf[2] = {hA, hB};
    for (int i = 0; i < 3; ++i) {
        k_dual_linear<<<512, 256, 0, stream>>>(cur, Wl + i * FF * HC, bl + i * HC,
                                               Wr + i * FF * HC, br + i * HC, xl, xr, nTiles);
        if (use_lg)
            k_gat_agg<1><<<NN / 8, 256, 0, stream>>>(xl, xr, rowptr, pairs,
                                                     att + i * HC, We + i * HC, cb + i * HC,
                                                     lg, outb);
        else
            k_gat_agg<0><<<NN / 8, 256, 0, stream>>>(xl, xr, rowptr, pairs,
                                                     att + i * HC, We + i * HC, cb + i * HC,
                                                     lg, outb);
        k_mlp_bn<<<512, 256, 0, stream>>>(outb, lW + i * HC * FF, lb + i * FF,
                                          bsc + i * FF, bsh + i * FF, hbuf[i & 1], nTiles);
        cur = hbuf[i & 1];
    }

    k_colsum<<<128, 256, 0, stream>>>(cur, g);
    k_head<<<1, 256, 0, stream>>>(g, W1, b1, W2, b2, W3, b3, (float*)d_out);
}

// Round 3
// 748.886 us; speedup vs baseline: 1.8213x; 1.0413x over previous
//
#include <hip/hip_runtime.h>
#include <hip/hip_bf16.h>
#include <math.h>

#define NN 50000
#define EE 800000
#define HC 128
#define FF 32
#define NEG 0.2f

// ---------------- CSR build ----------------

__global__ void k_hist(const int* __restrict__ dst, int* __restrict__ deg) {
    int e = blockIdx.x * 256 + threadIdx.x;
    if (e < EE) atomicAdd(&deg[dst[e]], 1);
}

// chunk = 1024 elements per block (256 thr x 4)
__global__ void k_scan1(const int* __restrict__ deg, int* __restrict__ part) {
    __shared__ int sd[256];
    int b = blockIdx.x, t = threadIdx.x;
    int base = b * 1024 + t * 4;
    int s = 0;
#pragma unroll
    for (int i = 0; i < 4; ++i) { int idx = base + i; if (idx < NN) s += deg[idx]; }
    sd[t] = s; __syncthreads();
    for (int off = 128; off; off >>= 1) { if (t < off) sd[t] += sd[t + off]; __syncthreads(); }
    if (t == 0) part[b] = sd[0];
}

__global__ void k_scan2(int* __restrict__ part, int nb) {
    if (threadIdx.x == 0) {
        int run = 0;
        for (int i = 0; i < nb; ++i) { int v = part[i]; part[i] = run; run += v; }
    }
}

__global__ void k_scan3(const int* __restrict__ deg, const int* __restrict__ part,
                        int* __restrict__ rowptr) {
    __shared__ int sd[256];
    int b = blockIdx.x, t = threadIdx.x;
    int base = b * 1024 + t * 4;
    int v[4]; int mine = 0;
#pragma unroll
    for (int i = 0; i < 4; ++i) { int idx = base + i; v[i] = (idx < NN) ? deg[idx] : 0; mine += v[i]; }
    sd[t] = mine; __syncthreads();
    for (int off = 1; off < 256; off <<= 1) {
        int tmp = (t >= off) ? sd[t - off] : 0;
        __syncthreads();
        sd[t] += tmp;
        __syncthreads();
    }
    int run = sd[t] - mine + part[b];
#pragma unroll
    for (int i = 0; i < 4; ++i) { int idx = base + i; if (idx < NN) rowptr[idx] = run; run += v[i]; }
    if (b == 0 && t == 0) rowptr[NN] = EE;
}

__global__ void k_scatter(const int* __restrict__ src, const int* __restrict__ dst,
                          const float* __restrict__ ea, const int* __restrict__ rowptr,
                          int* __restrict__ fill, int2* __restrict__ pairs) {
    int e = blockIdx.x * 256 + threadIdx.x;
    if (e >= EE) return;
    int d = dst[e];
    int pos = rowptr[d] + atomicAdd(&fill[d], 1);
    pairs[pos] = make_int2(src[e], __float_as_int(fabsf(ea[e])));
}

// ---------------- dual linear: xl = x@Wl+bl, xr = x@Wr+br ----------------
// Zero-LDS: thread <-> output column (256 = 128 xl + 128 xr), weights in 32
// registers hoisted over a grid-stride node loop, x row broadcast via shfl.

__global__ __launch_bounds__(256) void k_dual_linear(
        const float* __restrict__ x,
        const float* __restrict__ Wl, const float* __restrict__ bl,
        const float* __restrict__ Wr, const float* __restrict__ br,
        float* __restrict__ xl, float* __restrict__ xr) {
    const int t = threadIdx.x;
    const int cc = t & 127;
    const float* __restrict__ W = (t < 128) ? Wl : Wr;
    float wk[32];
#pragma unroll
    for (int k = 0; k < 32; ++k) wk[k] = W[k * 128 + cc];
    const float b = (t < 128) ? bl[cc] : br[cc];
    float* __restrict__ outp = (t < 128) ? xl : xr;
    const int lane = t & 31;
    for (int n = blockIdx.x; n < NN; n += gridDim.x) {
        float xrow = x[n * 32 + lane];
        float a0 = 0.f, a1 = 0.f, a2 = 0.f, a3 = 0.f;
#pragma unroll
        for (int k = 0; k < 32; k += 4) {
            a0 += __shfl(xrow, k,     32) * wk[k];
            a1 += __shfl(xrow, k + 1, 32) * wk[k + 1];
            a2 += __shfl(xrow, k + 2, 32) * wk[k + 2];
            a3 += __shfl(xrow, k + 3, 32) * wk[k + 3];
        }
        outp[n * 128 + cc] = b + ((a0 + a1) + (a2 + a3));
    }
}

// ---------------- fused GATv2 edge-softmax + aggregate (single pass) ----------------
// 32 threads per dst node (float4 = 4 channels each), 8 nodes per 256-block.
// Flash-style online softmax: rescale acc/s only when running max changes
// (group-uniform branch). Prefetch: pairs depth-4, xl rows depth-2.

__global__ __launch_bounds__(256) void k_gat_agg(
        const float* __restrict__ xl, const float* __restrict__ xr,
        const int* __restrict__ rowptr, const int2* __restrict__ pairs,
        const float* __restrict__ att,   // [128]
        const float* __restrict__ Wev,   // [128]
        const float* __restrict__ cb,    // [128]
        float* __restrict__ outb) {
    const int l = threadIdx.x & 31;
    const int n = blockIdx.x * 8 + (threadIdx.x >> 5);
    const float4* __restrict__ xl4 = (const float4*)xl;

    float4 att4 = ((const float4*)att)[l];
    float4 we4  = ((const float4*)Wev)[l];
    float4 xr4  = ((const float4*)xr)[n * 32 + l];
    const int beg = rowptr[n], end = rowptr[n + 1];

    float m = -INFINITY, s = 0.f;
    float4 acc = make_float4(0.f, 0.f, 0.f, 0.f);

    int2 p0 = make_int2(0, 0), p1 = p0, p2 = p0, p3 = p0;
    float4 x0 = make_float4(0.f, 0.f, 0.f, 0.f), x1 = x0;
    if (beg     < end) p0 = pairs[beg];
    if (beg + 1 < end) p1 = pairs[beg + 1];
    if (beg + 2 < end) p2 = pairs[beg + 2];
    if (beg + 3 < end) p3 = pairs[beg + 3];
    if (beg     < end) x0 = xl4[(size_t)p0.x * 32 + l];
    if (beg + 1 < end) x1 = xl4[(size_t)p1.x * 32 + l];

#pragma unroll 2
    for (int j = beg; j < end; ++j) {
        int2 pn = p0; float4 xn = x0;
        if (j + 4 < end) pn = pairs[j + 4];
        if (j + 2 < end) xn = xl4[(size_t)p2.x * 32 + l];

        float sea = __int_as_float(p0.y);
        float4 v;
        v.x = fmaf(sea, we4.x, xr4.x + x0.x);
        v.y = fmaf(sea, we4.y, xr4.y + x0.y);
        v.z = fmaf(sea, we4.z, xr4.z + x0.z);
        v.w = fmaf(sea, we4.w, xr4.w + x0.w);
        v.x = fmaxf(v.x, NEG * v.x);
        v.y = fmaxf(v.y, NEG * v.y);
        v.z = fmaxf(v.z, NEG * v.z);
        v.w = fmaxf(v.w, NEG * v.w);
        float pl = v.x * att4.x;
        pl = fmaf(v.y, att4.y, pl);
        pl = fmaf(v.z, att4.z, pl);
        pl = fmaf(v.w, att4.w, pl);
        pl += __shfl_xor(pl, 4);
        pl += __shfl_xor(pl, 2);
        pl += __shfl_xor(pl, 1);

        if (pl <= m) {                      // common path: max unchanged
            float e = __expf(pl - m);
            s += e;
            acc.x = fmaf(e, x0.x, acc.x);
            acc.y = fmaf(e, x0.y, acc.y);
            acc.z = fmaf(e, x0.z, acc.z);
            acc.w = fmaf(e, x0.w, acc.w);
        } else {                            // rare: rescale by exp(m - pl)
            float c = __expf(m - pl);
            s = fmaf(s, c, 1.f);
            acc.x = fmaf(acc.x, c, x0.x);
            acc.y = fmaf(acc.y, c, x0.y);
            acc.z = fmaf(acc.z, c, x0.z);
            acc.w = fmaf(acc.w, c, x0.w);
            m = pl;
        }
        p0 = p1; p1 = p2; p2 = p3; p3 = pn;
        x0 = x1; x1 = xn;
    }

    float inv = (s > 0.f) ? 1.f / s : 0.f;
    float4 cb4 = ((const float4*)cb)[l];
    float4 o;
    o.x = fmaf(acc.x, inv, cb4.x);
    o.y = fmaf(acc.y, inv, cb4.y);
    o.z = fmaf(acc.z, inv, cb4.z);
    o.w = fmaf(acc.w, inv, cb4.w);
    ((float4*)outb)[n * 32 + l] = o;
}

// ---------------- per-node MLP + BN: h = leaky(out@lW+lb)*bsc+bsh ----------------
// Zero-LDS: lane f holds lW[:,f] in 128 registers hoisted over node loop;
// out row (float4/lane) broadcast via shfl. 8 nodes per 256-block per tile.

__global__ __launch_bounds__(256) void k_mlp_bn(
        const float* __restrict__ outb,
        const float* __restrict__ lW, const float* __restrict__ lb,
        const float* __restrict__ bsc, const float* __restrict__ bsh,
        float* __restrict__ h) {
    const int t = threadIdx.x;
    const int f = t & 31;
    float w[128];
#pragma unroll
    for (int c = 0; c < 128; ++c) w[c] = lW[c * 32 + f];
    const float b = lb[f], sc = bsc[f], sh = bsh[f];
    const int slot = t >> 5;
    const float4* __restrict__ ob4 = (const float4*)outb;
    for (int n0 = blockIdx.x * 8; n0 < NN; n0 += gridDim.x * 8) {
        int n = n0 + slot;
        float4 o = ob4[n * 32 + f];   // channels 4f..4f+3 of node n's out row
        float a0 = 0.f, a1 = 0.f, a2 = 0.f, a3 = 0.f;
#pragma unroll
        for (int c = 0; c < 128; c += 4) {
            int sl = c >> 2;
            a0 = fmaf(__shfl(o.x, sl, 32), w[c],     a0);
            a1 = fmaf(__shfl(o.y, sl, 32), w[c + 1], a1);
            a2 = fmaf(__shfl(o.z, sl, 32), w[c + 2], a2);
            a3 = fmaf(__shfl(o.w, sl, 32), w[c + 3], a3);
        }
        float acc = b + ((a0 + a1) + (a2 + a3));
        acc = fmaxf(acc, NEG * acc);
        h[n * 32 + f] = fmaf(acc, sc, sh);
    }
}

// ---------------- global mean pool (column sums) ----------------

__global__ void k_colsum(const float* __restrict__ h, float* __restrict__ g) {
    __shared__ float sd[256];
    int t = threadIdx.x;
    int col = t & 31, r = t >> 5;
    float local = 0.f;
    for (int row = blockIdx.x * 8 + r; row < NN; row += gridDim.x * 8)
        local += h[row * FF + col];
    sd[t] = local; __syncthreads();
    if (r < 4) sd[t] += sd[t + 128];
    __syncthreads();
    if (r < 2) sd[t] += sd[t + 64];
    __syncthreads();
    if (r < 1) atomicAdd(&g[col], sd[t] + sd[t + 32]);
}

// ---------------- head MLP: 32 -> 256 -> 32 -> 2 ----------------

__global__ void k_head(const float* __restrict__ g,
                       const float* __restrict__ W1, const float* __restrict__ b1,
                       const float* __restrict__ W2, const float* __restrict__ b2,
                       const float* __restrict__ W3, const float* __restrict__ b3,
                       float* __restrict__ out) {
    __shared__ float gv[32];
    __shared__ float h1[256];
    __shared__ float h2[32];
    int t = threadIdx.x;
    if (t < 32) gv[t] = g[t] * (1.0f / NN);
    __syncthreads();
    float acc = b1[t];
#pragma unroll 8
    for (int k = 0; k < 32; ++k) acc += gv[k] * W1[k * 256 + t];
    h1[t] = acc > 0.f ? acc : NEG * acc;
    __syncthreads();
    if (t < 32) {
        float a = b2[t];
        for (int k = 0; k < 256; ++k) a += h1[k] * W2[k * 32 + t];
        h2[t] = a > 0.f ? a : NEG * a;
    }
    __syncthreads();
    if (t < 2) {
        float a = b3[t];
#pragma unroll
        for (int k = 0; k < 32; ++k) a += h2[k] * W3[k * 2 + t];
        out[t] = a;
    }
}

// ---------------- host ----------------

static inline size_t alignup(size_t x) { return (x + 255) & ~size_t(255); }

extern "C" void kernel_launch(void* const* d_in, const int* in_sizes, int n_in,
                              void* d_out, int out_size, void* d_ws, size_t ws_size,
                              hipStream_t stream) {
    const float* x     = (const float*)d_in[0];
    const int*   eidx  = (const int*)d_in[1];
    const float* eattr = (const float*)d_in[2];
    const float* Wl    = (const float*)d_in[4];
    const float* bl    = (const float*)d_in[5];
    const float* Wr    = (const float*)d_in[6];
    const float* br    = (const float*)d_in[7];
    const float* att   = (const float*)d_in[8];
    const float* We    = (const float*)d_in[9];
    const float* cb    = (const float*)d_in[10];
    const float* lW    = (const float*)d_in[11];
    const float* lb    = (const float*)d_in[12];
    const float* bsc   = (const float*)d_in[13];
    const float* bsh   = (const float*)d_in[14];
    const float* W1    = (const float*)d_in[15];
    const float* b1    = (const float*)d_in[16];
    const float* W2    = (const float*)d_in[17];
    const float* b2    = (const float*)d_in[18];
    const float* W3    = (const float*)d_in[19];
    const float* b3    = (const float*)d_in[20];

    const int* srcp = eidx;
    const int* dstp = eidx + EE;

    char* ws = (char*)d_ws;
    size_t off = 0;
    float* xl     = (float*)(ws + off); off += alignup((size_t)NN * HC * 4);
    float* xr     = (float*)(ws + off); off += alignup((size_t)NN * HC * 4);
    float* outb   = (float*)(ws + off); off += alignup((size_t)NN * HC * 4);
    float* hA     = (float*)(ws + off); off += alignup((size_t)NN * FF * 4);
    float* hB     = (float*)(ws + off); off += alignup((size_t)NN * FF * 4);
    int2*  pairs  = (int2*) (ws + off); off += alignup((size_t)EE * 8);
    int*   rowptr = (int*)  (ws + off); off += alignup((size_t)(NN + 1) * 4);
    int*   deg    = (int*)  (ws + off); off += alignup((size_t)NN * 4);
    int*   fill   = (int*)  (ws + off); off += alignup((size_t)NN * 4);
    int*   part   = (int*)  (ws + off); off += alignup(64 * 4);
    float* g      = (float*)(ws + off); off += alignup(32 * 4);

    hipMemsetAsync(deg, 0, (size_t)NN * 4, stream);
    hipMemsetAsync(fill, 0, (size_t)NN * 4, stream);
    hipMemsetAsync(g, 0, 32 * 4, stream);

    const int nChunk = (NN + 1023) / 1024;  // 49
    k_hist<<<(EE + 255) / 256, 256, 0, stream>>>(dstp, deg);
    k_scan1<<<nChunk, 256, 0, stream>>>(deg, part);
    k_scan2<<<1, 64, 0, stream>>>(part, nChunk);
    k_scan3<<<nChunk, 256, 0, stream>>>(deg, part, rowptr);
    k_scatter<<<(EE + 255) / 256, 256, 0, stream>>>(srcp, dstp, eattr, rowptr, fill, pairs);

    const float* cur = x;
    float* hbuf[2] = {hA, hB};
    for (int i = 0; i < 3; ++i) {
        k_dual_linear<<<1250, 256, 0, stream>>>(cur, Wl + i * FF * HC, bl + i * HC,
                                                Wr + i * FF * HC, br + i * HC, xl, xr);
        k_gat_agg<<<NN / 8, 256, 0, stream>>>(xl, xr, rowptr, pairs,
                                              att + i * HC, We + i * HC, cb + i * HC, outb);
        k_mlp_bn<<<1250, 256, 0, stream>>>(outb, lW + i * HC * FF, lb + i * FF,
                                           bsc + i * FF, bsh + i * FF, hbuf[i & 1]);
        cur = hbuf[i & 1];
    }

    k_colsum<<<128, 256, 0, stream>>>(cur, g);
    k_head<<<1, 256, 0, stream>>>(g, W1, b1, W2, b2, W3, b3, (float*)d_out);
}

// Round 4
// 555.229 us; speedup vs baseline: 2.4566x; 1.3488x over previous
//
#include <hip/hip_runtime.h>
#include <hip/hip_bf16.h>
#include <math.h>

#define NN 50000
#define EE 800000
#define HC 128
#define FF 32
#define NEG 0.2f

// ---------------- CSR build ----------------

__global__ void k_hist(const int* __restrict__ dst, int* __restrict__ deg) {
    int e = blockIdx.x * 256 + threadIdx.x;
    if (e < EE) atomicAdd(&deg[dst[e]], 1);
}

// chunk = 1024 elements per block (256 thr x 4)
__global__ void k_scan1(const int* __restrict__ deg, int* __restrict__ part) {
    __shared__ int sd[256];
    int b = blockIdx.x, t = threadIdx.x;
    int base = b * 1024 + t * 4;
    int s = 0;
#pragma unroll
    for (int i = 0; i < 4; ++i) { int idx = base + i; if (idx < NN) s += deg[idx]; }
    sd[t] = s; __syncthreads();
    for (int off = 128; off; off >>= 1) { if (t < off) sd[t] += sd[t + off]; __syncthreads(); }
    if (t == 0) part[b] = sd[0];
}

__global__ void k_scan2(int* __restrict__ part, int nb) {
    if (threadIdx.x == 0) {
        int run = 0;
        for (int i = 0; i < nb; ++i) { int v = part[i]; part[i] = run; run += v; }
    }
}

__global__ void k_scan3(const int* __restrict__ deg, const int* __restrict__ part,
                        int* __restrict__ rowptr) {
    __shared__ int sd[256];
    int b = blockIdx.x, t = threadIdx.x;
    int base = b * 1024 + t * 4;
    int v[4]; int mine = 0;
#pragma unroll
    for (int i = 0; i < 4; ++i) { int idx = base + i; v[i] = (idx < NN) ? deg[idx] : 0; mine += v[i]; }
    sd[t] = mine; __syncthreads();
    for (int off = 1; off < 256; off <<= 1) {
        int tmp = (t >= off) ? sd[t - off] : 0;
        __syncthreads();
        sd[t] += tmp;
        __syncthreads();
    }
    int run = sd[t] - mine + part[b];
#pragma unroll
    for (int i = 0; i < 4; ++i) { int idx = base + i; if (idx < NN) rowptr[idx] = run; run += v[i]; }
    if (b == 0 && t == 0) rowptr[NN] = EE;
}

__global__ void k_scatter(const int* __restrict__ src, const int* __restrict__ dst,
                          const float* __restrict__ ea, const int* __restrict__ rowptr,
                          int* __restrict__ fill, int2* __restrict__ pairs) {
    int e = blockIdx.x * 256 + threadIdx.x;
    if (e >= EE) return;
    int d = dst[e];
    int pos = rowptr[d] + atomicAdd(&fill[d], 1);
    pairs[pos] = make_int2(src[e], __float_as_int(fabsf(ea[e])));
}

// ---------------- dual linear: xl = x@Wl+bl, xr = x@Wr+br ----------------
// One wave per node. Lane l: half=l>>5 (xl/xr), cols 4*(l&31)..+3 with weights
// in 128 VGPRs. x row (8 quads) loaded replicated every 8 lanes, broadcast via
// width-8 shfl: 32 shfl + 128 wave-FMA per node (4 FMA per broadcast).

__global__ __launch_bounds__(256) void k_dual_linear(
        const float* __restrict__ x,
        const float* __restrict__ Wl, const float* __restrict__ bl,
        const float* __restrict__ Wr, const float* __restrict__ br,
        float* __restrict__ xl, float* __restrict__ xr) {
    const int t = threadIdx.x;
    const int l = t & 63;
    const int half = l >> 5;
    const int lc = l & 31;
    const float* __restrict__ W  = half ? Wr : Wl;
    const float* __restrict__ bb = half ? br : bl;
    float* __restrict__ outp     = half ? xr : xl;

    float4 w[32];
#pragma unroll
    for (int k = 0; k < 32; ++k)
        w[k] = *(const float4*)(W + k * 128 + 4 * lc);
    const float4 bias = *(const float4*)(bb + 4 * lc);

    const int gw = blockIdx.x * 4 + (t >> 6);
    const int nW = gridDim.x * 4;
    const int q8 = 4 * (l & 7);

    int n = gw;
    if (n >= NN) return;
    float4 r0 = *(const float4*)(x + (size_t)n * 32 + q8);
    int n1 = n + nW < NN ? n + nW : n;
    float4 r1 = *(const float4*)(x + (size_t)n1 * 32 + q8);

    for (; n < NN; n += nW) {
        float4 cur = r0;
        r0 = r1;
        int np = n + 2 * nW < NN ? n + 2 * nW : n;
        r1 = *(const float4*)(x + (size_t)np * 32 + q8);

        float4 acc = bias;
#pragma unroll
        for (int q = 0; q < 8; ++q) {
            float vx = __shfl(cur.x, q, 8);
            float vy = __shfl(cur.y, q, 8);
            float vz = __shfl(cur.z, q, 8);
            float vw = __shfl(cur.w, q, 8);
            acc.x = fmaf(vx, w[4 * q + 0].x, acc.x);
            acc.y = fmaf(vx, w[4 * q + 0].y, acc.y);
            acc.z = fmaf(vx, w[4 * q + 0].z, acc.z);
            acc.w = fmaf(vx, w[4 * q + 0].w, acc.w);
            acc.x = fmaf(vy, w[4 * q + 1].x, acc.x);
            acc.y = fmaf(vy, w[4 * q + 1].y, acc.y);
            acc.z = fmaf(vy, w[4 * q + 1].z, acc.z);
            acc.w = fmaf(vy, w[4 * q + 1].w, acc.w);
            acc.x = fmaf(vz, w[4 * q + 2].x, acc.x);
            acc.y = fmaf(vz, w[4 * q + 2].y, acc.y);
            acc.z = fmaf(vz, w[4 * q + 2].z, acc.z);
            acc.w = fmaf(vz, w[4 * q + 2].w, acc.w);
            acc.x = fmaf(vw, w[4 * q + 3].x, acc.x);
            acc.y = fmaf(vw, w[4 * q + 3].y, acc.y);
            acc.z = fmaf(vw, w[4 * q + 3].z, acc.z);
            acc.w = fmaf(vw, w[4 * q + 3].w, acc.w);
        }
        *(float4*)(outp + (size_t)n * 128 + 4 * lc) = acc;
    }
}

// ---------------- fused GATv2 edge-softmax + aggregate (single pass) ----------------

__global__ __launch_bounds__(256) void k_gat_agg(
        const float* __restrict__ xl, const float* __restrict__ xr,
        const int* __restrict__ rowptr, const int2* __restrict__ pairs,
        const float* __restrict__ att,   // [128]
        const float* __restrict__ Wev,   // [128]
        const float* __restrict__ cb,    // [128]
        float* __restrict__ outb) {
    const int l = threadIdx.x & 31;
    const int n = blockIdx.x * 8 + (threadIdx.x >> 5);
    const float4* __restrict__ xl4 = (const float4*)xl;

    float4 att4 = ((const float4*)att)[l];
    float4 we4  = ((const float4*)Wev)[l];
    float4 xr4  = ((const float4*)xr)[n * 32 + l];
    const int beg = rowptr[n], end = rowptr[n + 1];

    float m = -INFINITY, s = 0.f;
    float4 acc = make_float4(0.f, 0.f, 0.f, 0.f);

    int2 p0 = make_int2(0, 0), p1 = p0, p2 = p0, p3 = p0;
    float4 x0 = make_float4(0.f, 0.f, 0.f, 0.f), x1 = x0;
    if (beg     < end) p0 = pairs[beg];
    if (beg + 1 < end) p1 = pairs[beg + 1];
    if (beg + 2 < end) p2 = pairs[beg + 2];
    if (beg + 3 < end) p3 = pairs[beg + 3];
    if (beg     < end) x0 = xl4[(size_t)p0.x * 32 + l];
    if (beg + 1 < end) x1 = xl4[(size_t)p1.x * 32 + l];

#pragma unroll 2
    for (int j = beg; j < end; ++j) {
        int2 pn = p0; float4 xn = x0;
        if (j + 4 < end) pn = pairs[j + 4];
        if (j + 2 < end) xn = xl4[(size_t)p2.x * 32 + l];

        float sea = __int_as_float(p0.y);
        float4 v;
        v.x = fmaf(sea, we4.x, xr4.x + x0.x);
        v.y = fmaf(sea, we4.y, xr4.y + x0.y);
        v.z = fmaf(sea, we4.z, xr4.z + x0.z);
        v.w = fmaf(sea, we4.w, xr4.w + x0.w);
        v.x = fmaxf(v.x, NEG * v.x);
        v.y = fmaxf(v.y, NEG * v.y);
        v.z = fmaxf(v.z, NEG * v.z);
        v.w = fmaxf(v.w, NEG * v.w);
        float pl = v.x * att4.x;
        pl = fmaf(v.y, att4.y, pl);
        pl = fmaf(v.z, att4.z, pl);
        pl = fmaf(v.w, att4.w, pl);
        pl += __shfl_xor(pl, 4);
        pl += __shfl_xor(pl, 2);
        pl += __shfl_xor(pl, 1);

        if (pl <= m) {
            float e = __expf(pl - m);
            s += e;
            acc.x = fmaf(e, x0.x, acc.x);
            acc.y = fmaf(e, x0.y, acc.y);
            acc.z = fmaf(e, x0.z, acc.z);
            acc.w = fmaf(e, x0.w, acc.w);
        } else {
            float c = __expf(m - pl);
            s = fmaf(s, c, 1.f);
            acc.x = fmaf(acc.x, c, x0.x);
            acc.y = fmaf(acc.y, c, x0.y);
            acc.z = fmaf(acc.z, c, x0.z);
            acc.w = fmaf(acc.w, c, x0.w);
            m = pl;
        }
        p0 = p1; p1 = p2; p2 = p3; p3 = pn;
        x0 = x1; x1 = xn;
    }

    float inv = (s > 0.f) ? 1.f / s : 0.f;
    float4 cb4 = ((const float4*)cb)[l];
    float4 o;
    o.x = fmaf(acc.x, inv, cb4.x);
    o.y = fmaf(acc.y, inv, cb4.y);
    o.z = fmaf(acc.z, inv, cb4.z);
    o.w = fmaf(acc.w, inv, cb4.w);
    ((float4*)outb)[n * 32 + l] = o;
}

// ---------------- per-node MLP + BN: h = leaky(out@lW+lb)*bsc+bsh ----------------
// One wave per 2 nodes. Lane l: node half=l>>5, col-quad cg=(l>>2)&7 (cols
// 4cg..4cg+3), k-quarter kg=l&3 (k in [32kg,32kg+32)). Weights w[32] float4 in
// regs. Row (32 quads) held one quad/lane per half; width-32 shfl broadcast
// from lane 8*kg+j. Cross-kg reduce via 2 shfl_xor; lanes kg==0 store.

__global__ __launch_bounds__(256) void k_mlp_bn(
        const float* __restrict__ outb,
        const float* __restrict__ lW, const float* __restrict__ lb,
        const float* __restrict__ bsc, const float* __restrict__ bsh,
        float* __restrict__ h) {
    const int t = threadIdx.x;
    const int l = t & 63;
    const int half = l >> 5;
    const int cg = (l >> 2) & 7;
    const int kg = l & 3;

    float4 w[32];
#pragma unroll
    for (int kl = 0; kl < 32; ++kl)
        w[kl] = *(const float4*)(lW + (size_t)(32 * kg + kl) * 32 + 4 * cg);

    const float4 bias = (kg == 0) ? *(const float4*)(lb + 4 * cg)
                                  : make_float4(0.f, 0.f, 0.f, 0.f);
    const float4 sc4 = *(const float4*)(bsc + 4 * cg);
    const float4 sh4 = *(const float4*)(bsh + 4 * cg);

    const int gw = blockIdx.x * 4 + (t >> 6);
    const int nW = gridDim.x * 4;
    const int quad = 4 * (l & 31);
    const int kg8 = kg * 8;

    int p = gw;
    if (p >= NN / 2) return;
    float4 r0 = *(const float4*)(outb + (size_t)(2 * p + half) * 128 + quad);
    int p1i = p + nW < NN / 2 ? p + nW : p;
    float4 r1 = *(const float4*)(outb + (size_t)(2 * p1i + half) * 128 + quad);

    for (; p < NN / 2; p += nW) {
        float4 cur = r0;
        r0 = r1;
        int pp = p + 2 * nW < NN / 2 ? p + 2 * nW : p;
        r1 = *(const float4*)(outb + (size_t)(2 * pp + half) * 128 + quad);

        float4 acc = bias;
#pragma unroll
        for (int j = 0; j < 8; ++j) {
            float vx = __shfl(cur.x, kg8 + j, 32);
            float vy = __shfl(cur.y, kg8 + j, 32);
            float vz = __shfl(cur.z, kg8 + j, 32);
            float vw = __shfl(cur.w, kg8 + j, 32);
            acc.x = fmaf(vx, w[4 * j + 0].x, acc.x);
            acc.y = fmaf(vx, w[4 * j + 0].y, acc.y);
            acc.z = fmaf(vx, w[4 * j + 0].z, acc.z);
            acc.w = fmaf(vx, w[4 * j + 0].w, acc.w);
            acc.x = fmaf(vy, w[4 * j + 1].x, acc.x);
            acc.y = fmaf(vy, w[4 * j + 1].y, acc.y);
            acc.z = fmaf(vy, w[4 * j + 1].z, acc.z);
            acc.w = fmaf(vy, w[4 * j + 1].w, acc.w);
            acc.x = fmaf(vz, w[4 * j + 2].x, acc.x);
            acc.y = fmaf(vz, w[4 * j + 2].y, acc.y);
            acc.z = fmaf(vz, w[4 * j + 2].z, acc.z);
            acc.w = fmaf(vz, w[4 * j + 2].w, acc.w);
            acc.x = fmaf(vw, w[4 * j + 3].x, acc.x);
            acc.y = fmaf(vw, w[4 * j + 3].y, acc.y);
            acc.z = fmaf(vw, w[4 * j + 3].z, acc.z);
            acc.w = fmaf(vw, w[4 * j + 3].w, acc.w);
        }
        // reduce across kg (lanes differing in bits 0-1)
        acc.x += __shfl_xor(acc.x, 1); acc.x += __shfl_xor(acc.x, 2);
        acc.y += __shfl_xor(acc.y, 1); acc.y += __shfl_xor(acc.y, 2);
        acc.z += __shfl_xor(acc.z, 1); acc.z += __shfl_xor(acc.z, 2);
        acc.w += __shfl_xor(acc.w, 1); acc.w += __shfl_xor(acc.w, 2);

        if (kg == 0) {
            float4 o;
            o.x = fmaxf(acc.x, NEG * acc.x);
            o.y = fmaxf(acc.y, NEG * acc.y);
            o.z = fmaxf(acc.z, NEG * acc.z);
            o.w = fmaxf(acc.w, NEG * acc.w);
            o.x = fmaf(o.x, sc4.x, sh4.x);
            o.y = fmaf(o.y, sc4.y, sh4.y);
            o.z = fmaf(o.z, sc4.z, sh4.z);
            o.w = fmaf(o.w, sc4.w, sh4.w);
            *(float4*)(h + (size_t)(2 * p + half) * 32 + 4 * cg) = o;
        }
    }
}

// ---------------- global mean pool (column sums) ----------------

__global__ void k_colsum(const float* __restrict__ h, float* __restrict__ g) {
    __shared__ float sd[256];
    int t = threadIdx.x;
    int col = t & 31, r = t >> 5;
    float local = 0.f;
    for (int row = blockIdx.x * 8 + r; row < NN; row += gridDim.x * 8)
        local += h[row * FF + col];
    sd[t] = local; __syncthreads();
    if (r < 4) sd[t] += sd[t + 128];
    __syncthreads();
    if (r < 2) sd[t] += sd[t + 64];
    __syncthreads();
    if (r < 1) atomicAdd(&g[col], sd[t] + sd[t + 32]);
}

// ---------------- head MLP: 32 -> 256 -> 32 -> 2 ----------------

__global__ void k_head(const float* __restrict__ g,
                       const float* __restrict__ W1, const float* __restrict__ b1,
                       const float* __restrict__ W2, const float* __restrict__ b2,
                       const float* __restrict__ W3, const float* __restrict__ b3,
                       float* __restrict__ out) {
    __shared__ float gv[32];
    __shared__ float h1[256];
    __shared__ float h2[32];
    int t = threadIdx.x;
    if (t < 32) gv[t] = g[t] * (1.0f / NN);
    __syncthreads();
    float acc = b1[t];
#pragma unroll 8
    for (int k = 0; k < 32; ++k) acc += gv[k] * W1[k * 256 + t];
    h1[t] = acc > 0.f ? acc : NEG * acc;
    __syncthreads();
    if (t < 32) {
        float a = b2[t];
        for (int k = 0; k < 256; ++k) a += h1[k] * W2[k * 32 + t];
        h2[t] = a > 0.f ? a : NEG * a;
    }
    __syncthreads();
    if (t < 2) {
        float a = b3[t];
#pragma unroll
        for (int k = 0; k < 32; ++k) a += h2[k] * W3[k * 2 + t];
        out[t] = a;
    }
}

// ---------------- host ----------------

static inline size_t alignup(size_t x) { return (x + 255) & ~size_t(255); }

extern "C" void kernel_launch(void* const* d_in, const int* in_sizes, int n_in,
                              void* d_out, int out_size, void* d_ws, size_t ws_size,
                              hipStream_t stream) {
    const float* x     = (const float*)d_in[0];
    const int*   eidx  = (const int*)d_in[1];
    const float* eattr = (const float*)d_in[2];
    const float* Wl    = (const float*)d_in[4];
    const float* bl    = (const float*)d_in[5];
    const float* Wr    = (const float*)d_in[6];
    const float* br    = (const float*)d_in[7];
    const float* att   = (const float*)d_in[8];
    const float* We    = (const float*)d_in[9];
    const float* cb    = (const float*)d_in[10];
    const float* lW    = (const float*)d_in[11];
    const float* lb    = (const float*)d_in[12];
    const float* bsc   = (const float*)d_in[13];
    const float* bsh   = (const float*)d_in[14];
    const float* W1    = (const float*)d_in[15];
    const float* b1    = (const float*)d_in[16];
    const float* W2    = (const float*)d_in[17];
    const float* b2    = (const float*)d_in[18];
    const float* W3    = (const float*)d_in[19];
    const float* b3    = (const float*)d_in[20];

    const int* srcp = eidx;
    const int* dstp = eidx + EE;

    char* ws = (char*)d_ws;
    size_t off = 0;
    float* xl     = (float*)(ws + off); off += alignup((size_t)NN * HC * 4);
    float* xr     = (float*)(ws + off); off += alignup((size_t)NN * HC * 4);
    float* outb   = (float*)(ws + off); off += alignup((size_t)NN * HC * 4);
    float* hA     = (float*)(ws + off); off += alignup((size_t)NN * FF * 4);
    float* hB     = (float*)(ws + off); off += alignup((size_t)NN * FF * 4);
    int2*  pairs  = (int2*) (ws + off); off += alignup((size_t)EE * 8);
    int*   rowptr = (int*)  (ws + off); off += alignup((size_t)(NN + 1) * 4);
    int*   deg    = (int*)  (ws + off); off += alignup((size_t)NN * 4);
    int*   fill   = (int*)  (ws + off); off += alignup((size_t)NN * 4);
    int*   part   = (int*)  (ws + off); off += alignup(64 * 4);
    float* g      = (float*)(ws + off); off += alignup(32 * 4);

    hipMemsetAsync(deg, 0, (size_t)NN * 4, stream);
    hipMemsetAsync(fill, 0, (size_t)NN * 4, stream);
    hipMemsetAsync(g, 0, 32 * 4, stream);

    const int nChunk = (NN + 1023) / 1024;  // 49
    k_hist<<<(EE + 255) / 256, 256, 0, stream>>>(dstp, deg);
    k_scan1<<<nChunk, 256, 0, stream>>>(deg, part);
    k_scan2<<<1, 64, 0, stream>>>(part, nChunk);
    k_scan3<<<nChunk, 256, 0, stream>>>(deg, part, rowptr);
    k_scatter<<<(EE + 255) / 256, 256, 0, stream>>>(srcp, dstp, eattr, rowptr, fill, pairs);

    const float* cur = x;
    float* hbuf[2] = {hA, hB};
    for (int i = 0; i < 3; ++i) {
        k_dual_linear<<<768, 256, 0, stream>>>(cur, Wl + i * FF * HC, bl + i * HC,
                                               Wr + i * FF * HC, br + i * HC, xl, xr);
        k_gat_agg<<<NN / 8, 256, 0, stream>>>(xl, xr, rowptr, pairs,
                                              att + i * HC, We + i * HC, cb + i * HC, outb);
        k_mlp_bn<<<768, 256, 0, stream>>>(outb, lW + i * HC * FF, lb + i * FF,
                                          bsc + i * FF, bsh + i * FF, hbuf[i & 1]);
        cur = hbuf[i & 1];
    }

    k_colsum<<<128, 256, 0, stream>>>(cur, g);
    k_head<<<1, 256, 0, stream>>>(g, W1, b1, W2, b2, W3, b3, (float*)d_out);
}